// Round 16
// baseline (190.855 us; speedup 1.0000x reference)
//
#include <hip/hip_runtime.h>

typedef unsigned short u16;
typedef unsigned int u32;
typedef __bf16 bf16x8 __attribute__((ext_vector_type(8)));
typedef float f32x4 __attribute__((ext_vector_type(4)));
typedef float f32x16 __attribute__((ext_vector_type(16)));
typedef u16 u16x8 __attribute__((ext_vector_type(8)));
typedef u16 u16x4 __attribute__((ext_vector_type(4)));
typedef u32 u32x4 __attribute__((ext_vector_type(4)));

typedef __attribute__((address_space(1))) const unsigned char gc_u8;
typedef __attribute__((address_space(3))) unsigned char lds_u8;

__device__ inline void gload16(const void* g, void* l) {
    __builtin_amdgcn_global_load_lds((gc_u8*)g, (lds_u8*)l, 16, 0, 0);
}
__device__ inline u16 f2bf(float f) {
    union { __bf16 h; u16 u; } c; c.h = (__bf16)f; return c.u;
}
__device__ inline float bf2f(u16 u) {
    union { u16 u[2]; float f; } c; c.u[0] = 0; c.u[1] = u; return c.f;
}
__device__ inline u32 cvtpk(float lo, float hi) {   // D.lo=bf16(lo), D.hi=bf16(hi)
    u32 r;
    asm("v_cvt_pk_bf16_f32 %0, %1, %2" : "=v"(r) : "v"(lo), "v"(hi));
    return r;
}
__device__ inline void plswap(u32& a, u32& b) {     // a=[a_lo,b_lo], b=[a_hi,b_hi]
    asm("v_permlane32_swap_b32 %0, %1" : "+v"(a), "+v"(b));
}
// Fully-fenced barrier: nothing (incl. register-only ops / ds ops) crosses.
__device__ inline void hard_barrier() {
    __builtin_amdgcn_sched_barrier(0);
    __builtin_amdgcn_s_barrier();
    __builtin_amdgcn_sched_barrier(0);
}
#define WAIT_LGKM0() asm volatile("s_waitcnt lgkmcnt(0)" ::: "memory")
#define WAIT_VMCNT(n) asm volatile("s_waitcnt vmcnt(" #n ")" ::: "memory")

// ---------------- weight fp32 -> bf16 convert ----------------
__global__ __launch_bounds__(256) void cvt4(const float* __restrict__ s0,
                                            const float* __restrict__ s1,
                                            const float* __restrict__ s2,
                                            const float* __restrict__ s3,
                                            u16* __restrict__ d0, u16* __restrict__ d1,
                                            u16* __restrict__ d2, u16* __restrict__ d3,
                                            int n) {
    const int y = blockIdx.y;
    const float* src = (y == 0) ? s0 : (y == 1) ? s1 : (y == 2) ? s2 : s3;
    u16* dst = (y == 0) ? d0 : (y == 1) ? d1 : (y == 2) ? d2 : d3;
    int i = (blockIdx.x * 256 + threadIdx.x) * 4;
    if (i < n) {
        float4 f = *reinterpret_cast<const float4*>(src + i);
        u16x4 u = { f2bf(f.x), f2bf(f.y), f2bf(f.z), f2bf(f.w) };
        *reinterpret_cast<u16x4*>(dst + i) = u;
    }
}

// ---------------- merged QKV projection GEMM, f32-A direct (R13/R15-proven) ----------------
__global__ __launch_bounds__(256) void gemm_qkv(const float* __restrict__ Aq,
                                                const float* __restrict__ Ak,
                                                const float* __restrict__ Av,
                                                const u16* __restrict__ Bq,
                                                const u16* __restrict__ Bk,
                                                const u16* __restrict__ Bv,
                                                const float* __restrict__ bq,
                                                const float* __restrict__ bk,
                                                const float* __restrict__ bv,
                                                const int* __restrict__ Mk,
                                                u16* __restrict__ Cq,
                                                u16* __restrict__ Ck,
                                                u16* __restrict__ Cvp,
                                                int M, int N, int K) {
    __shared__ __align__(16) float Asf[2][128][32];
    __shared__ __align__(16) u16 Bs[2][128][32];
    const int z = blockIdx.z;
    const float* A = (z == 0) ? Aq : (z == 1) ? Ak : Av;
    const u16* B = (z == 0) ? Bq : (z == 1) ? Bk : Bv;
    const float* bias = (z == 0) ? bq : (z == 1) ? bk : bv;
    u16* Cv = (z == 0) ? Cq : (z == 1) ? Ck : Cvp;
    const bool vmode = (z == 2);

    const int t = threadIdx.x, lane = t & 63, w = t >> 6;
    const int wr = w >> 1, wc = w & 1;
    const int l15 = lane & 15, l16 = lane >> 4;
    const int nwg = gridDim.x, ntiles = N >> 7;
    const int wg = blockIdx.x, chunk = nwg >> 3;
    const int swz = (wg & 7) * chunk + (wg >> 3);
    const int bm = (swz / ntiles) * 128, bn = (swz % ntiles) * 128;
    const int srow = w * 16 + (lane >> 2);
    const int sgr = (lane & 3) * 8;
    const int arsub = lane >> 3;
    const int agr = ((lane & 7) ^ (lane >> 3)) * 4;
    const u16* Bb = B + (size_t)bn * K;

    f32x4 acc[4][4];
#pragma unroll
    for (int i = 0; i < 4; i++)
#pragma unroll
        for (int j = 0; j < 4; j++) acc[i][j] = (f32x4){0.f, 0.f, 0.f, 0.f};

    auto stage = [&](int c, int k0) {
#pragma unroll
        for (int ch = 0; ch < 4; ch++)
            gload16(A + (size_t)(bm + ch * 32 + w * 8 + arsub) * K + k0 + agr,
                    &Asf[c][ch * 32 + w * 8][0]);
        gload16(Bb + (size_t)srow * K + k0 + sgr,        &Bs[c][w * 16][0]);
        gload16(Bb + (size_t)(64 + srow) * K + k0 + sgr, &Bs[c][64 + w * 16][0]);
    };

    stage(0, 0);
    __syncthreads();

    const int NS = K >> 5;
    for (int i = 0; i < NS; ++i) {
        const int c = i & 1;
        WAIT_LGKM0();
        hard_barrier();
        if (i + 1 < NS) {
            stage(c ^ 1, (i + 1) * 32);
            WAIT_VMCNT(6);
        } else {
            WAIT_VMCNT(0);
        }
        hard_barrier();

        const int key = l15 & 7;
        bf16x8 afr[4], bfr[4];
#pragma unroll
        for (int mi = 0; mi < 4; mi++) {
            const int rr = wr * 64 + mi * 16 + l15;
            f32x4 lo = *(const f32x4*)&Asf[c][rr][((2 * l16) ^ key) * 4];
            f32x4 hi = *(const f32x4*)&Asf[c][rr][((2 * l16 + 1) ^ key) * 4];
            bf16x8 v;
            v[0] = (__bf16)lo[0]; v[1] = (__bf16)lo[1];
            v[2] = (__bf16)lo[2]; v[3] = (__bf16)lo[3];
            v[4] = (__bf16)hi[0]; v[5] = (__bf16)hi[1];
            v[6] = (__bf16)hi[2]; v[7] = (__bf16)hi[3];
            afr[mi] = v;
        }
#pragma unroll
        for (int ni = 0; ni < 4; ni++)
            bfr[ni] = *(const bf16x8*)&Bs[c][wc * 64 + ni * 16 + l15][l16 * 8];
#pragma unroll
        for (int mi = 0; mi < 4; mi++)
#pragma unroll
            for (int ni = 0; ni < 4; ni++)
                acc[mi][ni] = __builtin_amdgcn_mfma_f32_16x16x32_bf16(
                    afr[mi], bfr[ni], acc[mi][ni], 0, 0, 0);
    }

#pragma unroll
    for (int ni = 0; ni < 4; ni++) {
        const int col = bn + wc * 64 + ni * 16 + l15;
        const float bv2 = bias[col];
#pragma unroll
        for (int mi = 0; mi < 4; mi++) {
            const int r0 = bm + wr * 64 + mi * 16 + l16 * 4;
            if (vmode) {
                const int bb = r0 >> 11, ss = r0 & 2047;
                const int hh = col >> 6, dk = col & 63;
                const int4 m4 = *(const int4*)&Mk[bb * 2048 + ss];
                u16x4 pk;
                pk[0] = m4.x ? f2bf(acc[mi][ni][0] + bv2) : (u16)0;
                pk[1] = m4.y ? f2bf(acc[mi][ni][1] + bv2) : (u16)0;
                pk[2] = m4.z ? f2bf(acc[mi][ni][2] + bv2) : (u16)0;
                pk[3] = m4.w ? f2bf(acc[mi][ni][3] + bv2) : (u16)0;
                *(u16x4*)&Cv[(((size_t)(bb * 16 + hh) * 64 + dk) << 11) + ss] = pk;
            } else {
#pragma unroll
                for (int r = 0; r < 4; r++)
                    Cv[(size_t)(r0 + r) * N + col] = f2bf(acc[mi][ni][r] + bv2);
            }
        }
    }
}

// ---------------- out-projection GEMM (f32 out) — UNCHANGED ----------------
__global__ __launch_bounds__(256) void gemm_out(const u16* __restrict__ A,
                                                const u16* __restrict__ B,
                                                const float* __restrict__ bias,
                                                float* __restrict__ Cv,
                                                int M, int N, int K) {
    __shared__ __align__(16) u16 As[2][128][32];
    __shared__ __align__(16) u16 Bs[2][128][32];
    const int t = threadIdx.x, lane = t & 63, w = t >> 6;
    const int wr = w >> 1, wc = w & 1;
    const int l15 = lane & 15, l16 = lane >> 4;
    const int nwg = gridDim.x, ntiles = N >> 7;
    const int wg = blockIdx.x, chunk = nwg >> 3;
    const int swz = (wg & 7) * chunk + (wg >> 3);
    const int bm = (swz / ntiles) * 128, bn = (swz % ntiles) * 128;
    const int srow = w * 16 + (lane >> 2);
    const int sgr = (lane & 3) * 8;
    const u16* Ab = A + (size_t)bm * K;
    const u16* Bb = B + (size_t)bn * K;

    f32x4 acc[4][4];
#pragma unroll
    for (int i = 0; i < 4; i++)
#pragma unroll
        for (int j = 0; j < 4; j++) acc[i][j] = (f32x4){0.f, 0.f, 0.f, 0.f};

    auto stage = [&](int c, int k0) {
        gload16(Ab + (size_t)srow * K + k0 + sgr,        &As[c][w * 16][0]);
        gload16(Ab + (size_t)(64 + srow) * K + k0 + sgr, &As[c][64 + w * 16][0]);
        gload16(Bb + (size_t)srow * K + k0 + sgr,        &Bs[c][w * 16][0]);
        gload16(Bb + (size_t)(64 + srow) * K + k0 + sgr, &Bs[c][64 + w * 16][0]);
    };

    stage(0, 0);
    __syncthreads();

    const int NS = K >> 5;
    for (int i = 0; i < NS; ++i) {
        const int c = i & 1;
        WAIT_LGKM0();
        hard_barrier();
        if (i + 1 < NS) {
            stage(c ^ 1, (i + 1) * 32);
            WAIT_VMCNT(4);
        } else {
            WAIT_VMCNT(0);
        }
        hard_barrier();

        bf16x8 afr[4], bfr[4];
#pragma unroll
        for (int mi = 0; mi < 4; mi++)
            afr[mi] = *(const bf16x8*)&As[c][wr * 64 + mi * 16 + l15][l16 * 8];
#pragma unroll
        for (int ni = 0; ni < 4; ni++)
            bfr[ni] = *(const bf16x8*)&Bs[c][wc * 64 + ni * 16 + l15][l16 * 8];
#pragma unroll
        for (int mi = 0; mi < 4; mi++)
#pragma unroll
            for (int ni = 0; ni < 4; ni++)
                acc[mi][ni] = __builtin_amdgcn_mfma_f32_16x16x32_bf16(
                    afr[mi], bfr[ni], acc[mi][ni], 0, 0, 0);
    }

#pragma unroll
    for (int ni = 0; ni < 4; ni++) {
        const int col = bn + wc * 64 + ni * 16 + l15;
        const float bv = bias[col];
#pragma unroll
        for (int mi = 0; mi < 4; mi++) {
            const int r0 = bm + wr * 64 + mi * 16 + l16 * 4;
#pragma unroll
            for (int r = 0; r < 4; r++)
                Cv[(size_t)(r0 + r) * N + col] = acc[mi][ni][r] + bv;
        }
    }
}

// ---------------- flash attention: 32x32 MFMA, in-register P (no LDS bounce) ----------------
// R15 staging/fence skeleton (512 blocks, 4 waves x 64 q, KVBLK=128 dbuf, vmcnt(8)).
// Swapped QK via 32x32x16: lane(hb,l31) holds P[key=(r&3)+8(r>>2)+4hb][q=l31].
// P -> PV A-frag via cvt_pk + v_permlane32_swap (pure VALU; no ds_write/read, no lgkm).
// Mask folded: V cols zeroed (gemm_qkv) + lsum via 0/1 bf16 mask fragment MFMA.
__global__ __launch_bounds__(256, 2) void attn_fwd(const u16* __restrict__ Q,
                                                   const u16* __restrict__ Kg,
                                                   const u16* __restrict__ Vt,
                                                   const int* __restrict__ mask,
                                                   u16* __restrict__ O) {
    constexpr int S = 2048, D = 1024;
    __shared__ __align__(16) u16 Kl[2][2][2][64][32];  // [buf][kg][dk-half][key64][dk32]
    __shared__ __align__(16) u16 Vl[2][2][2][64][32];  // [buf][kg][k32-half][dk64][k32]
    __shared__ __align__(16) u16 Ml[2048];             // bf16 0/1 mask vector
    const int t = threadIdx.x, lane = t & 63, w = t >> 6;
    const int l31 = lane & 31, hb = lane >> 5;
    const int wg = blockIdx.x;                         // 512 blocks, %8==0 -> bijective
    const int swz = (wg & 7) * 64 + (wg >> 3);
    const int q0 = (swz & 7) * 256, hd = (swz >> 3) & 15, b = swz >> 7;
    const int qb = q0 + w * 64;
    const int srow = w * 16 + (lane >> 2);
    const int sgr = ((lane & 3) ^ ((lane >> 3) & 3)) * 8;   // pre-swizzled source granule
    const int rsw = (l31 >> 1) & 3;                         // read-swizzle key for row l31

    const u16* Khead = Kg + (size_t)b * S * D + hd * 64;
    const u16* Vthead = Vt + (size_t)(b * 16 + hd) * 64 * 2048;
    const int* mrow = mask + b * S;

    auto stage = [&](int c, int kt) {
#pragma unroll
        for (int kg = 0; kg < 2; kg++) {
            const int k0 = kt + kg * 64;
            gload16(Khead + (size_t)(k0 + srow) * D + sgr,        &Kl[c][kg][0][w * 16][0]);
            gload16(Khead + (size_t)(k0 + srow) * D + 32 + sgr,   &Kl[c][kg][1][w * 16][0]);
            gload16(Vthead + (size_t)srow * 2048 + k0 + sgr,      &Vl[c][kg][0][w * 16][0]);
            gload16(Vthead + (size_t)srow * 2048 + k0 + 32 + sgr, &Vl[c][kg][1][w * 16][0]);
        }
    };

    stage(0, 0);
    // build bf16 0/1 mask vector in LDS (one-time)
    {
        const int4 ia = *(const int4*)&mrow[t * 8];
        const int4 ib = *(const int4*)&mrow[t * 8 + 4];
        u16x8 mv;
        mv[0] = ia.x ? (u16)0x3F80 : (u16)0;
        mv[1] = ia.y ? (u16)0x3F80 : (u16)0;
        mv[2] = ia.z ? (u16)0x3F80 : (u16)0;
        mv[3] = ia.w ? (u16)0x3F80 : (u16)0;
        mv[4] = ib.x ? (u16)0x3F80 : (u16)0;
        mv[5] = ib.y ? (u16)0x3F80 : (u16)0;
        mv[6] = ib.z ? (u16)0x3F80 : (u16)0;
        mv[7] = ib.w ? (u16)0x3F80 : (u16)0;
        *(u16x8*)&Ml[t * 8] = mv;
    }

    // Q fragments: B-operand of 32x32x16, per q-tile (2) per dk-chunk (4):
    // lane(hb,l31) holds Q[qb + qt2*32 + l31][chunk*16 + hb*8 + j] * QSCALE
    constexpr float QSCALE = 0.125f * 1.44269504f;
    bf16x8 aq[2][4];
#pragma unroll
    for (int qt2 = 0; qt2 < 2; qt2++)
#pragma unroll
        for (int ch = 0; ch < 4; ch++) {
            const size_t qi = ((size_t)b * S + qb + qt2 * 32 + l31) * D +
                              hd * 64 + ch * 16 + hb * 8;
            u16x8 raw = *(const u16x8*)&Q[qi];
            bf16x8 qv;
#pragma unroll
            for (int i = 0; i < 8; i++) qv[i] = (__bf16)(bf2f(raw[i]) * QSCALE);
            aq[qt2][ch] = qv;
        }

    f32x16 acc[2][2];   // [qt2][dt2]
    f32x16 accl[2];     // [qt2] masked row-sums
#pragma unroll
    for (int qt2 = 0; qt2 < 2; qt2++) {
        accl[qt2] = (f32x16)(0.f);
#pragma unroll
        for (int dt2 = 0; dt2 < 2; dt2++) acc[qt2][dt2] = (f32x16)(0.f);
    }

    __syncthreads();  // one-time full drain: buf0 staged + Ml visible

    for (int tile = 0; tile < S / 128; ++tile) {
        const int c = tile & 1;
        const int cur = tile * 128;
        WAIT_LGKM0();
        hard_barrier();   // barrier1
        if (tile + 1 < S / 128) {
            stage(c ^ 1, cur + 128);
            WAIT_VMCNT(8);
        } else {
            WAIT_VMCNT(0);
        }
        hard_barrier();   // barrier2

#pragma unroll
        for (int kg = 0; kg < 2; kg++) {
#pragma unroll
            for (int kt2 = 0; kt2 < 2; kt2++) {
                // K A-frags: row = kt2*32+l31, dk chunk ch: granule (ch&1)*2+hb, half ch>>1
                bf16x8 kf[4];
#pragma unroll
                for (int ch = 0; ch < 4; ch++)
                    kf[ch] = *(const bf16x8*)&Kl[c][kg][ch >> 1][kt2 * 32 + l31]
                                               [(((ch & 1) * 2 + hb) ^ rsw) * 8];
                // V B-frags: row = dt2*32+l31 (dk), key half kt2, window wd: granule wd*2+hb
                bf16x8 vf[2][2];
#pragma unroll
                for (int dt2 = 0; dt2 < 2; dt2++)
#pragma unroll
                    for (int wd = 0; wd < 2; wd++)
                        vf[dt2][wd] = *(const bf16x8*)&Vl[c][kg][kt2][dt2 * 32 + l31]
                                                        [((wd * 2 + hb) ^ rsw) * 8];
                // mask B-frags (broadcast): keys kbase + hb*8 + j
                const int kbase = cur + kg * 64 + kt2 * 32;
                bf16x8 mf0 = *(const bf16x8*)&Ml[kbase + hb * 8];
                bf16x8 mf1 = *(const bf16x8*)&Ml[kbase + 16 + hb * 8];

#pragma unroll
                for (int qt2 = 0; qt2 < 2; qt2++) {
                    f32x16 zz = (f32x16)(0.f);
#pragma unroll
                    for (int ch = 0; ch < 4; ch++)
                        zz = __builtin_amdgcn_mfma_f32_32x32x16_bf16(kf[ch], aq[qt2][ch],
                                                                     zz, 0, 0, 0);
                    float p[16];
#pragma unroll
                    for (int r = 0; r < 16; r++) p[r] = __builtin_amdgcn_exp2f(zz[r]);

                    // window 0 (keys kbase..kbase+15): regs 0-7
                    u32 a0 = cvtpk(p[0], p[1]), b0 = cvtpk(p[2], p[3]);
                    u32 c0 = cvtpk(p[4], p[5]), d0 = cvtpk(p[6], p[7]);
                    plswap(a0, c0);
                    plswap(b0, d0);
                    u32x4 w0 = {a0, b0, c0, d0};
                    bf16x8 pf0 = *(bf16x8*)&w0;
                    // window 1 (keys kbase+16..+31): regs 8-15
                    u32 a1 = cvtpk(p[8], p[9]),  b1 = cvtpk(p[10], p[11]);
                    u32 c1 = cvtpk(p[12], p[13]), d1 = cvtpk(p[14], p[15]);
                    plswap(a1, c1);
                    plswap(b1, d1);
                    u32x4 w1 = {a1, b1, c1, d1};
                    bf16x8 pf1 = *(bf16x8*)&w1;

                    accl[qt2] = __builtin_amdgcn_mfma_f32_32x32x16_bf16(pf0, mf0,
                                                                        accl[qt2], 0, 0, 0);
                    accl[qt2] = __builtin_amdgcn_mfma_f32_32x32x16_bf16(pf1, mf1,
                                                                        accl[qt2], 0, 0, 0);
#pragma unroll
                    for (int dt2 = 0; dt2 < 2; dt2++) {
                        acc[qt2][dt2] = __builtin_amdgcn_mfma_f32_32x32x16_bf16(
                            pf0, vf[dt2][0], acc[qt2][dt2], 0, 0, 0);
                        acc[qt2][dt2] = __builtin_amdgcn_mfma_f32_32x32x16_bf16(
                            pf1, vf[dt2][1], acc[qt2][dt2], 0, 0, 0);
                    }
                }
            }
        }
    }

    // epilogue: q = qt2*32 + (r&3)+8*(r>>2)+4*hb, d = dt2*32 + l31
#pragma unroll
    for (int qt2 = 0; qt2 < 2; qt2++) {
        f32x16 inv;
#pragma unroll
        for (int r = 0; r < 16; r++) inv[r] = 1.f / accl[qt2][r];
#pragma unroll
        for (int dt2 = 0; dt2 < 2; dt2++)
#pragma unroll
            for (int r = 0; r < 16; r++) {
                const int q = qt2 * 32 + (r & 3) + 8 * (r >> 2) + 4 * hb;
                O[((size_t)b * S + qb + q) * D + hd * 64 + dt2 * 32 + l31] =
                    f2bf(acc[qt2][dt2][r] * inv[r]);
            }
    }
}

extern "C" void kernel_launch(void* const* d_in, const int* in_sizes, int n_in,
                              void* d_out, int out_size, void* d_ws, size_t ws_size,
                              hipStream_t stream) {
    const float* query = (const float*)d_in[0];
    const float* key   = (const float*)d_in[1];
    const float* value = (const float*)d_in[2];
    const int*   mask  = (const int*)d_in[3];
    const float* Wq = (const float*)d_in[4];
    const float* bq = (const float*)d_in[5];
    const float* Wk = (const float*)d_in[6];
    const float* bk = (const float*)d_in[7];
    const float* Wv = (const float*)d_in[8];
    const float* bv = (const float*)d_in[9];
    const float* Wo = (const float*)d_in[10];
    const float* bo = (const float*)d_in[11];
    float* out = (float*)d_out;

    constexpr int S = 2048, D = 1024;
    constexpr size_t MSZ = (size_t)4 * S * D;   // 8388608
    constexpr size_t WSZ = (size_t)D * D;       // 1048576
    const size_t need = 4 * WSZ * 2 + 4 * MSZ * 2;  // 72 MB
    if (ws_size < need) return;

    char* p = (char*)d_ws;
    u16* Wqb = (u16*)p; p += WSZ * 2;
    u16* Wkb = (u16*)p; p += WSZ * 2;
    u16* Wvb = (u16*)p; p += WSZ * 2;
    u16* Wob = (u16*)p; p += WSZ * 2;
    u16* Xb  = (u16*)p; p += MSZ * 2;  // attn output
    u16* Qb  = (u16*)p; p += MSZ * 2;
    u16* Kb  = (u16*)p; p += MSZ * 2;
    u16* Vtb = (u16*)p; p += MSZ * 2;  // (b,h,dk,s), masked cols zeroed

    cvt4<<<dim3(WSZ / 1024, 4), 256, 0, stream>>>(Wq, Wk, Wv, Wo,
                                                  Wqb, Wkb, Wvb, Wob, (int)WSZ);
    gemm_qkv<<<dim3(512, 1, 3), 256, 0, stream>>>(query, key, value,
                                                  Wqb, Wkb, Wvb, bq, bk, bv, mask,
                                                  Qb, Kb, Vtb, 8192, 1024, 1024);
    attn_fwd<<<512, 256, 0, stream>>>(Qb, Kb, Vtb, mask, Xb);
    gemm_out<<<512, 256, 0, stream>>>(Xb, Wob, bo, out, 8192, 1024, 1024);
}